// Round 1
// 984.359 us; speedup vs baseline: 4.3917x; 4.3917x over previous
//
#include <hip/hip_runtime.h>
#include <math.h>

// Problem constants
#define B_    2
#define S_    2048
#define H_    4096
#define NH_   32
#define NKV_  2
#define HD_   128
#define ROT_  64
#define NQKV_ 4608          // (NH + 2*NKV) * HD
#define M_    4096          // B * S
#define SCALE_ 0.088388347648318447f  // 1/sqrt(128)

typedef __attribute__((ext_vector_type(8))) short s16x8;
typedef __attribute__((ext_vector_type(4))) float f32x4;

__device__ __forceinline__ unsigned short f2bf(float x) {
  union { float f; unsigned u; } v; v.f = x;
  unsigned r = (v.u + 0x7fffu + ((v.u >> 16) & 1u)) >> 16;
  return (unsigned short)r;
}
__device__ __forceinline__ float bf2f(unsigned short u) {
  union { unsigned u; float f; } v; v.u = ((unsigned)u) << 16;
  return v.f;
}
// async global->LDS, 16B per lane; LDS dest is wave-uniform base + lane*16
__device__ __forceinline__ void gl_lds16(const unsigned short* g, unsigned short* l) {
  __builtin_amdgcn_global_load_lds(
      (const __attribute__((address_space(1))) void*)g,
      (__attribute__((address_space(3))) void*)l, 16, 0, 0);
}

// ---------------------------------------------------------------------------
// fp32 -> bf16 elementwise convert (hidden_states). n must be multiple of 8.
// ---------------------------------------------------------------------------
__global__ __launch_bounds__(256) void cvt_bf16_kernel(
    const float* __restrict__ in, unsigned short* __restrict__ o, long n)
{
  long i = ((long)blockIdx.x * blockDim.x + threadIdx.x) * 8;
  if (i >= n) return;
  float4 a = *(const float4*)(in + i);
  float4 b = *(const float4*)(in + i + 4);
  s16x8 v;
  v[0] = f2bf(a.x); v[1] = f2bf(a.y); v[2] = f2bf(a.z); v[3] = f2bf(a.w);
  v[4] = f2bf(b.x); v[5] = f2bf(b.y); v[6] = f2bf(b.z); v[7] = f2bf(b.w);
  *(s16x8*)(o + i) = v;
}

// ---------------------------------------------------------------------------
// Weight transpose + convert: wt[n][k] (bf16, N x K row-major) <- w[k][n]
// (fp32, K x N row-major). 64x64 tiles through LDS. K,N multiples of 64.
// ---------------------------------------------------------------------------
__global__ __launch_bounds__(256) void wtrans_kernel(
    const float* __restrict__ w, unsigned short* __restrict__ wt, int K, int N)
{
  __shared__ __align__(16) unsigned short T[64][72];
  const int tid = threadIdx.x;
  const int k0 = blockIdx.x * 64;
  const int n0 = blockIdx.y * 64;

#pragma unroll
  for (int i = 0; i < 4; ++i) {
    int idx = tid + i * 256;
    int kr = idx >> 4;             // 0..63 (k within tile)
    int nc = (idx & 15) << 2;      // 0..60 step 4
    float4 v = *(const float4*)(w + (size_t)(k0 + kr) * N + n0 + nc);
    T[nc + 0][kr] = f2bf(v.x);
    T[nc + 1][kr] = f2bf(v.y);
    T[nc + 2][kr] = f2bf(v.z);
    T[nc + 3][kr] = f2bf(v.w);
  }
  __syncthreads();
#pragma unroll
  for (int i = 0; i < 2; ++i) {
    int idx = tid + i * 256;
    int nr = idx >> 3;             // 0..63
    int kc = (idx & 7) << 3;       // 0..56 step 8
    s16x8 v = *(const s16x8*)&T[nr][kc];
    *(s16x8*)&wt[(size_t)(n0 + nr) * K + k0 + kc] = v;
  }
}

// ---------------------------------------------------------------------------
// bf16 MFMA GEMM (m97 structure): C = A @ Bt^T (+ bias).
// A: M x K bf16 row-major. Bt: N x K bf16 row-major. C: fp32 or bf16, M x N.
// 128x128 tile, BK=32, 4 waves, each wave 64x64 (4x4 frags of 16x16x32).
// Staging via global_load_lds dwordx4 (linear LDS layout [row][k], stride 32).
// ---------------------------------------------------------------------------
template<bool BF16OUT>
__global__ __launch_bounds__(256) void gemm_bf16_kernel(
    const unsigned short* __restrict__ A, const unsigned short* __restrict__ Bt,
    const float* __restrict__ bias, void* __restrict__ Cv,
    int M, int N, int K)
{
  __shared__ __align__(16) unsigned short As[128 * 32];
  __shared__ __align__(16) unsigned short Bs[128 * 32];
  const int tid  = threadIdx.x;
  const int lane = tid & 63;
  const int w    = tid >> 6;        // wave 0..3
  const int quad = lane >> 4;       // 0..3
  const int l15  = lane & 15;
  const int wm   = w >> 1;          // wave row block (0..1)
  const int wn   = w & 1;           // wave col block (0..1)
  const int bm = blockIdx.y * 128;
  const int bn = blockIdx.x * 128;

  // staging: 8 chunks of 16 rows each for A and B; wave w owns chunks {2w, 2w+1}
  const int r16 = lane >> 2;        // row within 16-row chunk
  const int kc  = (lane & 3) << 3;  // k element offset (0,8,16,24)
  const int c0  = w * 2;
  const unsigned short* Ag0 = A  + (size_t)(bm + (c0 + 0) * 16 + r16) * K + kc;
  const unsigned short* Ag1 = A  + (size_t)(bm + (c0 + 1) * 16 + r16) * K + kc;
  const unsigned short* Bg0 = Bt + (size_t)(bn + (c0 + 0) * 16 + r16) * K + kc;
  const unsigned short* Bg1 = Bt + (size_t)(bn + (c0 + 1) * 16 + r16) * K + kc;
  unsigned short* As0 = &As[(c0 + 0) * 512];  // wave-uniform LDS bases
  unsigned short* As1 = &As[(c0 + 1) * 512];
  unsigned short* Bs0 = &Bs[(c0 + 0) * 512];
  unsigned short* Bs1 = &Bs[(c0 + 1) * 512];

  // fragment read bases: A row = wm*64 + mi*16 + l15, k = quad*8 + j
  const unsigned short* Af = &As[(wm * 64 + l15) * 32 + (quad << 3)];
  const unsigned short* Bf = &Bs[(wn * 64 + l15) * 32 + (quad << 3)];

  f32x4 acc[4][4];
#pragma unroll
  for (int i = 0; i < 4; ++i)
#pragma unroll
    for (int j = 0; j < 4; ++j)
#pragma unroll
      for (int e = 0; e < 4; ++e) acc[i][j][e] = 0.0f;

  for (int k0 = 0; k0 < K; k0 += 32) {
    gl_lds16(Ag0 + k0, As0);
    gl_lds16(Ag1 + k0, As1);
    gl_lds16(Bg0 + k0, Bs0);
    gl_lds16(Bg1 + k0, Bs1);
    __syncthreads();               // drains vmcnt -> tiles resident
    s16x8 af[4], bfr[4];
#pragma unroll
    for (int mi = 0; mi < 4; ++mi) af[mi]  = *(const s16x8*)(Af + mi * 512);
#pragma unroll
    for (int ni = 0; ni < 4; ++ni) bfr[ni] = *(const s16x8*)(Bf + ni * 512);
#pragma unroll
    for (int mi = 0; mi < 4; ++mi)
#pragma unroll
      for (int ni = 0; ni < 4; ++ni)
        acc[mi][ni] = __builtin_amdgcn_mfma_f32_16x16x32_bf16(
            af[mi], bfr[ni], acc[mi][ni], 0, 0, 0);
    __syncthreads();               // all waves done reading before restage
  }

  float bv[4];
#pragma unroll
  for (int ni = 0; ni < 4; ++ni)
    bv[ni] = bias ? bias[bn + wn * 64 + ni * 16 + l15] : 0.0f;

#pragma unroll
  for (int mi = 0; mi < 4; ++mi)
#pragma unroll
    for (int i = 0; i < 4; ++i) {
      size_t row = (size_t)(bm + wm * 64 + mi * 16 + (quad << 2) + i);
#pragma unroll
      for (int ni = 0; ni < 4; ++ni) {
        size_t idx = row * N + bn + wn * 64 + ni * 16 + l15;
        float val = acc[mi][ni][i] + bv[ni];
        if (BF16OUT) ((unsigned short*)Cv)[idx] = f2bf(val);
        else         ((float*)Cv)[idx] = val;
      }
    }
}

// ---------------------------------------------------------------------------
// RoPE (GLM interleaved, first ROT dims of q and k heads), in-place bf16.
// ---------------------------------------------------------------------------
__global__ __launch_bounds__(256) void rope_kernel(
    unsigned short* __restrict__ qkv, const int* __restrict__ positions)
{
  int t = blockIdx.x * blockDim.x + threadIdx.x;
  const int total = M_ * (NH_ + NKV_) * (ROT_ / 2);
  if (t >= total) return;
  int pair = t & 31;
  int hh   = (t >> 5) % (NH_ + NKV_);
  int tok  = t / (32 * (NH_ + NKV_));
  int col  = hh * HD_;
  float pos  = (float)positions[tok];
  float freq = powf(10000.0f, -(float)pair * (1.0f / 32.0f));
  float ang  = pos * freq;
  float s = sinf(ang), c = cosf(ang);
  size_t base = (size_t)tok * NQKV_ + col + 2 * pair;   // even -> 4B aligned
  unsigned v = *(const unsigned*)(qkv + base);
  float x1 = bf2f((unsigned short)(v & 0xffffu));
  float x2 = bf2f((unsigned short)(v >> 16));
  float o1 = x1 * c - x2 * s;
  float o2 = x1 * s + x2 * c;
  *(unsigned*)(qkv + base) = (unsigned)f2bf(o1) | ((unsigned)f2bf(o2) << 16);
}

// ---------------------------------------------------------------------------
// V transpose (bf16 -> bf16): vt[bg][c][s] <- qkv V part [b][s][g*128+c].
// 64x64 tiles through LDS; bg = b*NKV + g.
// ---------------------------------------------------------------------------
__global__ __launch_bounds__(256) void vtrans_kernel(
    const unsigned short* __restrict__ qkv, unsigned short* __restrict__ vt)
{
  __shared__ __align__(16) unsigned short T[64][72];
  const int tid = threadIdx.x;
  const int s0 = blockIdx.x * 64;
  const int c0 = blockIdx.y * 64;
  const int bg = blockIdx.z;
  const int b = bg >> 1, g = bg & 1;

#pragma unroll
  for (int i = 0; i < 2; ++i) {
    int idx = tid + i * 256;       // 0..511
    int sr = idx >> 3;             // 0..63 (token within tile)
    int cc = (idx & 7) << 3;       // 0..56 step 8
    const unsigned short* p = qkv + (size_t)(b * S_ + s0 + sr) * NQKV_
                     + (NH_ + NKV_) * HD_ + g * HD_ + c0 + cc;
    s16x8 v = *(const s16x8*)p;
#pragma unroll
    for (int j = 0; j < 8; ++j) T[cc + j][sr] = (unsigned short)v[j];
  }
  __syncthreads();
#pragma unroll
  for (int i = 0; i < 2; ++i) {
    int idx = tid + i * 256;
    int cr = idx >> 3;             // 0..63
    int kc = idx & 7;              // 16B chunk within 64 tokens
    s16x8 v = *(const s16x8*)&T[cr][kc << 3];
    *(s16x8*)&vt[(size_t)((bg << 7) + c0 + cr) * S_ + s0 + (kc << 3)] = v;
  }
}

// ---------------------------------------------------------------------------
// Flash attention, bf16 MFMA, causal, GQA. bf16 in (qkv), bf16 out (attn).
// Block: 64 q-rows of one (b,h), 4 waves (16 rows each), K-tiles of 64.
// LDS (uint16 elements):
//   [0, 8704)        Ks[key][e], stride 136 (2-way conflicts only)
//   [8704, 16896)    Vt[col][key] 64 keys/row, XOR-chunk swizzle (also Qs at init)
//   [16896, 21504)   Ps[4 waves][16 rows][stride 72]
// Softmax scale applied to S in fp32 after QK^T (Q staged unscaled).
// ---------------------------------------------------------------------------
#define QS_OFF 8704
#define VT_OFF 8704
#define PS_OFF 16896

__global__ __launch_bounds__(256) void flash_mfma_kernel(
    const unsigned short* __restrict__ qkv, const unsigned short* __restrict__ vt,
    unsigned short* __restrict__ out)
{
  __shared__ __align__(16) unsigned short smem[21504];

  const int tid  = threadIdx.x;
  const int lane = tid & 63;
  const int w    = tid >> 6;        // wave 0..3
  const int quad = lane >> 4;       // 0..3
  const int l15  = lane & 15;
  const int q0 = blockIdx.x * 64;
  const int b  = blockIdx.y >> 5;
  const int h  = blockIdx.y & 31;
  const int g  = h >> 4;
  const int bg = b * NKV_ + g;
  const size_t tok0 = (size_t)b * S_;

  // ---- Stage Q (64x128 bf16, pure copy) ----
#pragma unroll
  for (int i = 0; i < 4; ++i) {
    int idx = tid + i * 256;                 // 0..1023
    int r = idx >> 4, c8 = (idx & 15) << 3;
    s16x8 v = *(const s16x8*)(qkv + (tok0 + q0 + r) * NQKV_ + h * HD_ + c8);
    *(s16x8*)&smem[QS_OFF + r * 136 + c8] = v;
  }
  __syncthreads();

  // Q fragments: A-operand, m = l15 (row within wave's 16), k = quad*8 + ks*32 + j
  s16x8 qf[4];
#pragma unroll
  for (int ks = 0; ks < 4; ++ks)
    qf[ks] = *(const s16x8*)&smem[QS_OFF + (w * 16 + l15) * 136 + (quad << 3) + (ks << 5)];
  __syncthreads();  // all waves done reading Qs before Vt overwrites it

  f32x4 O[8];
#pragma unroll
  for (int n = 0; n < 8; ++n)
#pragma unroll
    for (int i = 0; i < 4; ++i) O[n][i] = 0.0f;
  float m_i[4] = {-INFINITY, -INFINITY, -INFINITY, -INFINITY};
  float l_i[4] = {0.f, 0.f, 0.f, 0.f};

  for (int kt = 0; kt <= q0; kt += 64) {
    // ---- Stage K tile (64x128 bf16, pure copy) ----
#pragma unroll
    for (int i = 0; i < 4; ++i) {
      int idx = tid + i * 256;
      int key = idx >> 4, c8 = (idx & 15) << 3;
      s16x8 v = *(const s16x8*)(qkv + (tok0 + kt + key) * NQKV_ + NH_ * HD_ + g * HD_ + c8);
      *(s16x8*)&smem[key * 136 + c8] = v;
    }
    // ---- Stage V tile from pre-transposed bf16 (col-major, chunk swizzle) ----
#pragma unroll
    for (int i = 0; i < 4; ++i) {
      int idx = tid + i * 256;
      int c = idx >> 3, kc = idx & 7;
      s16x8 v = *(const s16x8*)&vt[(size_t)((bg << 7) + c) * S_ + kt + (kc << 3)];
      *(s16x8*)&smem[VT_OFF + (c << 6) + (((kc + c) & 7) << 3)] = v;
    }
    __syncthreads();

    // ---- S = Q K^T (4 n-tiles of 16 keys, K=128 over 4 MFMA steps) ----
    f32x4 S[4];
#pragma unroll
    for (int nt = 0; nt < 4; ++nt) {
#pragma unroll
      for (int i = 0; i < 4; ++i) S[nt][i] = 0.0f;
#pragma unroll
      for (int ks = 0; ks < 4; ++ks) {
        s16x8 kf = *(const s16x8*)&smem[(nt * 16 + l15) * 136 + (quad << 3) + (ks << 5)];
        S[nt] = __builtin_amdgcn_mfma_f32_16x16x32_bf16(qf[ks], kf, S[nt], 0, 0, 0);
      }
#pragma unroll
      for (int i = 0; i < 4; ++i) S[nt][i] *= SCALE_;
    }

    // ---- causal mask on diagonal tile ----
    if (kt == q0) {
#pragma unroll
      for (int nt = 0; nt < 4; ++nt) {
        int colL = nt * 16 + l15;
#pragma unroll
        for (int i = 0; i < 4; ++i) {
          int rowL = w * 16 + quad * 4 + i;
          if (colL > rowL) S[nt][i] = -INFINITY;
        }
      }
    }

    // ---- online softmax (rows = quad*4+i, reduce over l15 lanes + nt) ----
    float mx[4], alpha[4], rs[4];
#pragma unroll
    for (int i = 0; i < 4; ++i) {
      mx[i] = fmaxf(fmaxf(S[0][i], S[1][i]), fmaxf(S[2][i], S[3][i]));
#pragma unroll
      for (int off = 1; off < 16; off <<= 1)
        mx[i] = fmaxf(mx[i], __shfl_xor(mx[i], off));
      float mn = fmaxf(m_i[i], mx[i]);
      alpha[i] = __expf(m_i[i] - mn);   // exp(-inf) = 0 on first tile
      m_i[i] = mn;
      rs[i] = 0.0f;
    }
#pragma unroll
    for (int nt = 0; nt < 4; ++nt)
#pragma unroll
      for (int i = 0; i < 4; ++i) {
        float p = __expf(S[nt][i] - m_i[i]);
        S[nt][i] = p;
        rs[i] += p;
      }
#pragma unroll
    for (int i = 0; i < 4; ++i) {
#pragma unroll
      for (int off = 1; off < 16; off <<= 1)
        rs[i] += __shfl_xor(rs[i], off);
      l_i[i] = l_i[i] * alpha[i] + rs[i];
    }

    // ---- write P (bf16) to per-wave LDS, C-layout -> A-layout transform ----
#pragma unroll
    for (int nt = 0; nt < 4; ++nt)
#pragma unroll
      for (int i = 0; i < 4; ++i)
        smem[PS_OFF + (w * 16 + quad * 4 + i) * 72 + nt * 16 + l15] = f2bf(S[nt][i]);

    // ---- rescale O ----
#pragma unroll
    for (int n = 0; n < 8; ++n)
#pragma unroll
      for (int i = 0; i < 4; ++i) O[n][i] *= alpha[i];

    __syncthreads();  // Ps visible (and keeps waves off next staging)

    // ---- O += P V ----
    s16x8 pf[2];
#pragma unroll
    for (int ks2 = 0; ks2 < 2; ++ks2)
      pf[ks2] = *(const s16x8*)&smem[PS_OFF + (w * 16 + l15) * 72 + (quad << 3) + (ks2 << 5)];
#pragma unroll
    for (int nt2 = 0; nt2 < 8; ++nt2) {
      int col = nt2 * 16 + l15;
#pragma unroll
      for (int ks2 = 0; ks2 < 2; ++ks2) {
        int kc = ks2 * 4 + quad;
        s16x8 vf = *(const s16x8*)&smem[VT_OFF + (col << 6) + (((kc + col) & 7) << 3)];
        O[nt2] = __builtin_amdgcn_mfma_f32_16x16x32_bf16(pf[ks2], vf, O[nt2], 0, 0, 0);
      }
    }
    __syncthreads();  // done with Ks/Vt before next tile's staging
  }

  // ---- epilogue: O / l, write bf16 (feeds dense GEMM A-operand) ----
  float inv[4];
#pragma unroll
  for (int i = 0; i < 4; ++i) inv[i] = 1.0f / l_i[i];
#pragma unroll
  for (int nt2 = 0; nt2 < 8; ++nt2)
#pragma unroll
    for (int i = 0; i < 4; ++i) {
      size_t row = tok0 + q0 + w * 16 + quad * 4 + i;
      out[row * H_ + h * HD_ + nt2 * 16 + l15] = f2bf(O[nt2][i] * inv[i]);
    }
}

// ---------------------------------------------------------------------------
// Workspace / buffer plan (ws need = 71.3 MB; prior passing kernel used
// 77.6 MB of ws unconditionally, so this fits):
//   phase A (QKV GEMM):   ws[0,33.5M)   = hidden_bf16
//                         ws[33.5M,71.3M) = w_qkv^T bf16
//                         qkv bf16 (37.75 MB) -> lives in d_out (67 MB)
//   phase B (attn+dense): ws[0,2M)      = vt (V transposed bf16)
//                         ws[2M,35.7M)  = attn bf16
//                         ws[35.7M,69.2M) = w_dense^T bf16
//                         dense GEMM reads ws, writes d_out fp32 (no alias)
// ---------------------------------------------------------------------------
extern "C" void kernel_launch(void* const* d_in, const int* in_sizes, int n_in,
                              void* d_out, int out_size, void* d_ws, size_t ws_size,
                              hipStream_t stream)
{
  (void)in_sizes; (void)n_in; (void)out_size; (void)ws_size;
  const float* hidden    = (const float*)d_in[0];
  const float* w_qkv     = (const float*)d_in[1];
  const float* b_qkv     = (const float*)d_in[2];
  const float* w_dense   = (const float*)d_in[3];
  const int*   positions = (const int*)d_in[4];
  float* out = (float*)d_out;

  unsigned short* hbf   = (unsigned short*)d_ws;                      // 33.5 MB
  unsigned short* wqkvT = (unsigned short*)((char*)d_ws + 33554432);  // 37.75 MB
  unsigned short* vtb   = (unsigned short*)d_ws;                      // 2 MB (over dead hbf)
  unsigned short* abf   = (unsigned short*)((char*)d_ws + 2097152);   // 33.5 MB
  unsigned short* wdT   = (unsigned short*)((char*)d_ws + 35651584);  // 33.5 MB
  unsigned short* qkvb  = (unsigned short*)d_out;                     // 37.75 MB scratch in out

  // 1) convert hidden to bf16; transpose+convert w_qkv
  cvt_bf16_kernel<<<8192, 256, 0, stream>>>(hidden, hbf, (long)M_ * H_);
  wtrans_kernel<<<dim3(H_ / 64, NQKV_ / 64), 256, 0, stream>>>(w_qkv, wqkvT, H_, NQKV_);

  // 2) qkv = hidden @ w_qkv + b_qkv  (bf16 MFMA, bf16 out into d_out scratch)
  gemm_bf16_kernel<true><<<dim3(NQKV_ / 128, M_ / 128), 256, 0, stream>>>(
      hbf, wqkvT, b_qkv, qkvb, M_, NQKV_, H_);

  // 3) RoPE in-place (bf16 RMW)
  {
    int total = M_ * (NH_ + NKV_) * (ROT_ / 2);
    rope_kernel<<<(total + 255) / 256, 256, 0, stream>>>(qkvb, positions);
  }

  // 4) V transpose (bf16); transpose+convert w_dense (hbf/wqkvT now dead)
  vtrans_kernel<<<dim3(S_ / 64, HD_ / 64, B_ * NKV_), 256, 0, stream>>>(qkvb, vtb);
  wtrans_kernel<<<dim3(H_ / 64, H_ / 64), 256, 0, stream>>>(w_dense, wdT, H_, H_);

  // 5) causal GQA flash attention (bf16 MFMA), attn written as bf16
  flash_mfma_kernel<<<dim3(S_ / 64, B_ * NH_), 256, 0, stream>>>(qkvb, vtb, abf);

  // 6) out = attn @ w_dense (bf16 MFMA, fp32 out; overwrites qkv scratch)
  gemm_bf16_kernel<false><<<dim3(H_ / 128, M_ / 128), 256, 0, stream>>>(
      abf, wdT, nullptr, out, M_, H_, H_);
}

// Round 2
// 922.513 us; speedup vs baseline: 4.6861x; 1.0670x over previous
//
#include <hip/hip_runtime.h>
#include <math.h>

// Problem constants
#define B_    2
#define S_    2048
#define H_    4096
#define NH_   32
#define NKV_  2
#define HD_   128
#define ROT_  64
#define NQKV_ 4608          // (NH + 2*NKV) * HD
#define M_    4096          // B * S
#define SCALE_ 0.088388347648318447f  // 1/sqrt(128)

typedef __attribute__((ext_vector_type(8))) short s16x8;
typedef __attribute__((ext_vector_type(4))) float f32x4;

__device__ __forceinline__ unsigned short f2bf(float x) {
  union { float f; unsigned u; } v; v.f = x;
  unsigned r = (v.u + 0x7fffu + ((v.u >> 16) & 1u)) >> 16;
  return (unsigned short)r;
}
__device__ __forceinline__ float bf2f(unsigned short u) {
  union { unsigned u; float f; } v; v.u = ((unsigned)u) << 16;
  return v.f;
}
// async global->LDS, 16B per lane; LDS dest is wave-uniform base + lane*16
__device__ __forceinline__ void gl_lds16(const unsigned short* g, unsigned short* l) {
  __builtin_amdgcn_global_load_lds(
      (const __attribute__((address_space(1))) void*)g,
      (__attribute__((address_space(3))) void*)l, 16, 0, 0);
}

// ---------------------------------------------------------------------------
// fp32 -> bf16 elementwise convert (hidden_states). n must be multiple of 8.
// ---------------------------------------------------------------------------
__global__ __launch_bounds__(256) void cvt_bf16_kernel(
    const float* __restrict__ in, unsigned short* __restrict__ o, long n)
{
  long i = ((long)blockIdx.x * blockDim.x + threadIdx.x) * 8;
  if (i >= n) return;
  float4 a = *(const float4*)(in + i);
  float4 b = *(const float4*)(in + i + 4);
  s16x8 v;
  v[0] = f2bf(a.x); v[1] = f2bf(a.y); v[2] = f2bf(a.z); v[3] = f2bf(a.w);
  v[4] = f2bf(b.x); v[5] = f2bf(b.y); v[6] = f2bf(b.z); v[7] = f2bf(b.w);
  *(s16x8*)(o + i) = v;
}

// ---------------------------------------------------------------------------
// Weight transpose + convert: wt[n][k] (bf16, N x K row-major) <- w[k][n]
// (fp32, K x N row-major). 64x64 tiles through LDS. K,N multiples of 64.
// ---------------------------------------------------------------------------
__global__ __launch_bounds__(256) void wtrans_kernel(
    const float* __restrict__ w, unsigned short* __restrict__ wt, int K, int N)
{
  __shared__ __align__(16) unsigned short T[64][72];
  const int tid = threadIdx.x;
  const int k0 = blockIdx.x * 64;
  const int n0 = blockIdx.y * 64;

#pragma unroll
  for (int i = 0; i < 4; ++i) {
    int idx = tid + i * 256;
    int kr = idx >> 4;             // 0..63 (k within tile)
    int nc = (idx & 15) << 2;      // 0..60 step 4
    float4 v = *(const float4*)(w + (size_t)(k0 + kr) * N + n0 + nc);
    T[nc + 0][kr] = f2bf(v.x);
    T[nc + 1][kr] = f2bf(v.y);
    T[nc + 2][kr] = f2bf(v.z);
    T[nc + 3][kr] = f2bf(v.w);
  }
  __syncthreads();
#pragma unroll
  for (int i = 0; i < 2; ++i) {
    int idx = tid + i * 256;
    int nr = idx >> 3;             // 0..63
    int kc = (idx & 7) << 3;       // 0..56 step 8
    s16x8 v = *(const s16x8*)&T[nr][kc];
    *(s16x8*)&wt[(size_t)(n0 + nr) * K + k0 + kc] = v;
  }
}

// ---------------------------------------------------------------------------
// bf16 MFMA GEMM (m97 structure): C = A @ Bt^T (+ bias).
// A: M x K bf16 row-major. Bt: N x K bf16 row-major. C: fp32 or bf16, M x N.
// 128x128 tile, BK=32, 4 waves, each wave 64x64 (4x4 frags of 16x16x32).
// Staging via global_load_lds dwordx4 (linear LDS layout [row][k], stride 32).
// ---------------------------------------------------------------------------
template<bool BF16OUT>
__global__ __launch_bounds__(256) void gemm_bf16_kernel(
    const unsigned short* __restrict__ A, const unsigned short* __restrict__ Bt,
    const float* __restrict__ bias, void* __restrict__ Cv,
    int M, int N, int K)
{
  __shared__ __align__(16) unsigned short As[128 * 32];
  __shared__ __align__(16) unsigned short Bs[128 * 32];
  const int tid  = threadIdx.x;
  const int lane = tid & 63;
  const int w    = tid >> 6;        // wave 0..3
  const int quad = lane >> 4;       // 0..3
  const int l15  = lane & 15;
  const int wm   = w >> 1;          // wave row block (0..1)
  const int wn   = w & 1;           // wave col block (0..1)
  const int bm = blockIdx.y * 128;
  const int bn = blockIdx.x * 128;

  // staging: 8 chunks of 16 rows each for A and B; wave w owns chunks {2w, 2w+1}
  const int r16 = lane >> 2;        // row within 16-row chunk
  const int kc  = (lane & 3) << 3;  // k element offset (0,8,16,24)
  const int c0  = w * 2;
  const unsigned short* Ag0 = A  + (size_t)(bm + (c0 + 0) * 16 + r16) * K + kc;
  const unsigned short* Ag1 = A  + (size_t)(bm + (c0 + 1) * 16 + r16) * K + kc;
  const unsigned short* Bg0 = Bt + (size_t)(bn + (c0 + 0) * 16 + r16) * K + kc;
  const unsigned short* Bg1 = Bt + (size_t)(bn + (c0 + 1) * 16 + r16) * K + kc;
  unsigned short* As0 = &As[(c0 + 0) * 512];  // wave-uniform LDS bases
  unsigned short* As1 = &As[(c0 + 1) * 512];
  unsigned short* Bs0 = &Bs[(c0 + 0) * 512];
  unsigned short* Bs1 = &Bs[(c0 + 1) * 512];

  // fragment read bases: A row = wm*64 + mi*16 + l15, k = quad*8 + j
  const unsigned short* Af = &As[(wm * 64 + l15) * 32 + (quad << 3)];
  const unsigned short* Bf = &Bs[(wn * 64 + l15) * 32 + (quad << 3)];

  f32x4 acc[4][4];
#pragma unroll
  for (int i = 0; i < 4; ++i)
#pragma unroll
    for (int j = 0; j < 4; ++j)
#pragma unroll
      for (int e = 0; e < 4; ++e) acc[i][j][e] = 0.0f;

  for (int k0 = 0; k0 < K; k0 += 32) {
    gl_lds16(Ag0 + k0, As0);
    gl_lds16(Ag1 + k0, As1);
    gl_lds16(Bg0 + k0, Bs0);
    gl_lds16(Bg1 + k0, Bs1);
    __syncthreads();               // drains vmcnt -> tiles resident
    s16x8 af[4], bfr[4];
#pragma unroll
    for (int mi = 0; mi < 4; ++mi) af[mi]  = *(const s16x8*)(Af + mi * 512);
#pragma unroll
    for (int ni = 0; ni < 4; ++ni) bfr[ni] = *(const s16x8*)(Bf + ni * 512);
#pragma unroll
    for (int mi = 0; mi < 4; ++mi)
#pragma unroll
      for (int ni = 0; ni < 4; ++ni)
        acc[mi][ni] = __builtin_amdgcn_mfma_f32_16x16x32_bf16(
            af[mi], bfr[ni], acc[mi][ni], 0, 0, 0);
    __syncthreads();               // all waves done reading before restage
  }

  float bv[4];
#pragma unroll
  for (int ni = 0; ni < 4; ++ni)
    bv[ni] = bias ? bias[bn + wn * 64 + ni * 16 + l15] : 0.0f;

#pragma unroll
  for (int mi = 0; mi < 4; ++mi)
#pragma unroll
    for (int i = 0; i < 4; ++i) {
      size_t row = (size_t)(bm + wm * 64 + mi * 16 + (quad << 2) + i);
#pragma unroll
      for (int ni = 0; ni < 4; ++ni) {
        size_t idx = row * N + bn + wn * 64 + ni * 16 + l15;
        float val = acc[mi][ni][i] + bv[ni];
        if (BF16OUT) ((unsigned short*)Cv)[idx] = f2bf(val);
        else         ((float*)Cv)[idx] = val;
      }
    }
}

// ---------------------------------------------------------------------------
// RoPE (GLM interleaved, first ROT dims of q and k heads), in-place bf16.
// ---------------------------------------------------------------------------
__global__ __launch_bounds__(256) void rope_kernel(
    unsigned short* __restrict__ qkv, const int* __restrict__ positions)
{
  int t = blockIdx.x * blockDim.x + threadIdx.x;
  const int total = M_ * (NH_ + NKV_) * (ROT_ / 2);
  if (t >= total) return;
  int pair = t & 31;
  int hh   = (t >> 5) % (NH_ + NKV_);
  int tok  = t / (32 * (NH_ + NKV_));
  int col  = hh * HD_;
  float pos  = (float)positions[tok];
  float freq = powf(10000.0f, -(float)pair * (1.0f / 32.0f));
  float ang  = pos * freq;
  float s = sinf(ang), c = cosf(ang);
  size_t base = (size_t)tok * NQKV_ + col + 2 * pair;   // even -> 4B aligned
  unsigned v = *(const unsigned*)(qkv + base);
  float x1 = bf2f((unsigned short)(v & 0xffffu));
  float x2 = bf2f((unsigned short)(v >> 16));
  float o1 = x1 * c - x2 * s;
  float o2 = x1 * s + x2 * c;
  *(unsigned*)(qkv + base) = (unsigned)f2bf(o1) | ((unsigned)f2bf(o2) << 16);
}

// ---------------------------------------------------------------------------
// V transpose (bf16 -> bf16): vt[bg][c][s] <- qkv V part [b][s][g*128+c].
// 64x64 tiles through LDS; bg = b*NKV + g.
// ---------------------------------------------------------------------------
__global__ __launch_bounds__(256) void vtrans_kernel(
    const unsigned short* __restrict__ qkv, unsigned short* __restrict__ vt)
{
  __shared__ __align__(16) unsigned short T[64][72];
  const int tid = threadIdx.x;
  const int s0 = blockIdx.x * 64;
  const int c0 = blockIdx.y * 64;
  const int bg = blockIdx.z;
  const int b = bg >> 1, g = bg & 1;

#pragma unroll
  for (int i = 0; i < 2; ++i) {
    int idx = tid + i * 256;       // 0..511
    int sr = idx >> 3;             // 0..63 (token within tile)
    int cc = (idx & 7) << 3;       // 0..56 step 8
    const unsigned short* p = qkv + (size_t)(b * S_ + s0 + sr) * NQKV_
                     + (NH_ + NKV_) * HD_ + g * HD_ + c0 + cc;
    s16x8 v = *(const s16x8*)p;
#pragma unroll
    for (int j = 0; j < 8; ++j) T[cc + j][sr] = (unsigned short)v[j];
  }
  __syncthreads();
#pragma unroll
  for (int i = 0; i < 2; ++i) {
    int idx = tid + i * 256;
    int cr = idx >> 3;             // 0..63
    int kc = idx & 7;              // 16B chunk within 64 tokens
    s16x8 v = *(const s16x8*)&T[cr][kc << 3];
    *(s16x8*)&vt[(size_t)((bg << 7) + c0 + cr) * S_ + s0 + (kc << 3)] = v;
  }
}

// ---------------------------------------------------------------------------
// Flash attention, bf16 MFMA, causal, GQA. bf16 in (qkv), bf16 out (attn).
// Block: 128 q-rows of one (b,h), 4 waves; each wave owns two 16-row m-groups
// (rows mt*64 + w*16 .. +15). K-tiles of 64 keys.
// LDS (uint16 elements):
//   [0, 8704)        Ks[key][e], stride 136 (2-way conflicts only; also Q staging)
//   [8704, 16896)    Vt[col][key] 64 keys/row, XOR-chunk swizzle
//   [16896, 26112)   Ps[128 rows][stride 72]
// Shared kf/vf fragments feed both m-groups -> 2x MFMA per LDS read + per barrier.
// ---------------------------------------------------------------------------
#define VT_OFF 8704
#define PS_OFF 16896

__global__ __launch_bounds__(256, 2) void flash_mfma_kernel(
    const unsigned short* __restrict__ qkv, const unsigned short* __restrict__ vt,
    unsigned short* __restrict__ out)
{
  __shared__ __align__(16) unsigned short smem[26112];

  const int tid  = threadIdx.x;
  const int lane = tid & 63;
  const int w    = tid >> 6;        // wave 0..3
  const int quad = lane >> 4;       // 0..3
  const int l15  = lane & 15;
  const int q0 = blockIdx.x * 128;
  const int b  = blockIdx.y >> 5;
  const int h  = blockIdx.y & 31;
  const int g  = h >> 4;
  const int bg = b * NKV_ + g;
  const size_t tok0 = (size_t)b * S_;

  // ---- Stage Q (two 64-row halves through the Ks region), keep frags ----
  s16x8 qf[2][4];
#pragma unroll
  for (int mt = 0; mt < 2; ++mt) {
#pragma unroll
    for (int i = 0; i < 4; ++i) {
      int idx = tid + i * 256;                 // 0..1023
      int r = idx >> 4, c8 = (idx & 15) << 3;
      s16x8 v = *(const s16x8*)(qkv + (tok0 + q0 + mt * 64 + r) * NQKV_ + h * HD_ + c8);
      *(s16x8*)&smem[r * 136 + c8] = v;
    }
    __syncthreads();
#pragma unroll
    for (int ks = 0; ks < 4; ++ks)
      qf[mt][ks] = *(const s16x8*)&smem[(w * 16 + l15) * 136 + (quad << 3) + (ks << 5)];
    __syncthreads();  // all waves done reading before restage
  }

  f32x4 O[2][8];
#pragma unroll
  for (int mt = 0; mt < 2; ++mt)
#pragma unroll
    for (int n = 0; n < 8; ++n)
#pragma unroll
      for (int i = 0; i < 4; ++i) O[mt][n][i] = 0.0f;
  float m_i[2][4], l_i[2][4];
#pragma unroll
  for (int mt = 0; mt < 2; ++mt)
#pragma unroll
    for (int i = 0; i < 4; ++i) { m_i[mt][i] = -INFINITY; l_i[mt][i] = 0.f; }

  const int ktend = q0 + 64;   // rows reach q0+127 -> last k-tile starts at q0+64
  for (int kt = 0; kt <= ktend; kt += 64) {
    // ---- Stage K tile (64x128 bf16, pure copy) ----
#pragma unroll
    for (int i = 0; i < 4; ++i) {
      int idx = tid + i * 256;
      int key = idx >> 4, c8 = (idx & 15) << 3;
      s16x8 v = *(const s16x8*)(qkv + (tok0 + kt + key) * NQKV_ + NH_ * HD_ + g * HD_ + c8);
      *(s16x8*)&smem[key * 136 + c8] = v;
    }
    // ---- Stage V tile from pre-transposed bf16 (col-major, chunk swizzle) ----
#pragma unroll
    for (int i = 0; i < 4; ++i) {
      int idx = tid + i * 256;
      int c = idx >> 3, kc = idx & 7;
      s16x8 v = *(const s16x8*)&vt[(size_t)((bg << 7) + c) * S_ + kt + (kc << 3)];
      *(s16x8*)&smem[VT_OFF + (c << 6) + (((kc + c) & 7) << 3)] = v;
    }
    __syncthreads();

    // ---- S = Q K^T: kf shared by both m-groups ----
    f32x4 S[2][4];
#pragma unroll
    for (int mt = 0; mt < 2; ++mt)
#pragma unroll
      for (int nt = 0; nt < 4; ++nt)
#pragma unroll
        for (int i = 0; i < 4; ++i) S[mt][nt][i] = 0.0f;
#pragma unroll
    for (int nt = 0; nt < 4; ++nt) {
#pragma unroll
      for (int ks = 0; ks < 4; ++ks) {
        s16x8 kf = *(const s16x8*)&smem[(nt * 16 + l15) * 136 + (quad << 3) + (ks << 5)];
#pragma unroll
        for (int mt = 0; mt < 2; ++mt)
          S[mt][nt] = __builtin_amdgcn_mfma_f32_16x16x32_bf16(qf[mt][ks], kf, S[mt][nt], 0, 0, 0);
      }
#pragma unroll
      for (int mt = 0; mt < 2; ++mt)
#pragma unroll
        for (int i = 0; i < 4; ++i) S[mt][nt][i] *= SCALE_;
    }

    // ---- causal mask (only tiles at/past each m-group's diagonal) ----
#pragma unroll
    for (int mt = 0; mt < 2; ++mt) {
      if (kt >= q0 + mt * 64) {
#pragma unroll
        for (int nt = 0; nt < 4; ++nt) {
          int colG = kt + nt * 16 + l15;
#pragma unroll
          for (int i = 0; i < 4; ++i) {
            int rowG = q0 + mt * 64 + w * 16 + quad * 4 + i;
            if (colG > rowG) S[mt][nt][i] = -INFINITY;
          }
        }
      }
    }

    // ---- online softmax per m-group (rows = quad*4+i, reduce over l15 + nt) ----
    float alpha[2][4];
#pragma unroll
    for (int mt = 0; mt < 2; ++mt) {
      float mx[4], rs[4];
#pragma unroll
      for (int i = 0; i < 4; ++i) {
        mx[i] = fmaxf(fmaxf(S[mt][0][i], S[mt][1][i]), fmaxf(S[mt][2][i], S[mt][3][i]));
#pragma unroll
        for (int off = 1; off < 16; off <<= 1)
          mx[i] = fmaxf(mx[i], __shfl_xor(mx[i], off));
        float mn = fmaxf(m_i[mt][i], mx[i]);
        alpha[mt][i] = __expf(m_i[mt][i] - mn);   // exp(-inf)=0 on first tile
        m_i[mt][i] = mn;
        rs[i] = 0.0f;
      }
#pragma unroll
      for (int nt = 0; nt < 4; ++nt)
#pragma unroll
        for (int i = 0; i < 4; ++i) {
          float p = __expf(S[mt][nt][i] - m_i[mt][i]);
          S[mt][nt][i] = p;
          rs[i] += p;
        }
#pragma unroll
      for (int i = 0; i < 4; ++i) {
#pragma unroll
        for (int off = 1; off < 16; off <<= 1)
          rs[i] += __shfl_xor(rs[i], off);
        l_i[mt][i] = l_i[mt][i] * alpha[mt][i] + rs[i];
      }

      // ---- write P (bf16) to LDS, C-layout -> A-layout transform ----
#pragma unroll
      for (int nt = 0; nt < 4; ++nt)
#pragma unroll
        for (int i = 0; i < 4; ++i)
          smem[PS_OFF + (mt * 64 + w * 16 + quad * 4 + i) * 72 + nt * 16 + l15]
              = f2bf(S[mt][nt][i]);

      // ---- rescale O ----
#pragma unroll
      for (int n = 0; n < 8; ++n)
#pragma unroll
        for (int i = 0; i < 4; ++i) O[mt][n][i] *= alpha[mt][i];
    }

    __syncthreads();  // Ps visible (and keeps waves off next staging)

    // ---- O += P V : vf shared by both m-groups ----
    s16x8 pf[2][2];
#pragma unroll
    for (int mt = 0; mt < 2; ++mt)
#pragma unroll
      for (int ks2 = 0; ks2 < 2; ++ks2)
        pf[mt][ks2] = *(const s16x8*)&smem[PS_OFF + (mt * 64 + w * 16 + l15) * 72
                                           + (quad << 3) + (ks2 << 5)];
#pragma unroll
    for (int nt2 = 0; nt2 < 8; ++nt2) {
      int col = nt2 * 16 + l15;
#pragma unroll
      for (int ks2 = 0; ks2 < 2; ++ks2) {
        int kc = ks2 * 4 + quad;
        s16x8 vf = *(const s16x8*)&smem[VT_OFF + (col << 6) + (((kc + col) & 7) << 3)];
#pragma unroll
        for (int mt = 0; mt < 2; ++mt)
          O[mt][nt2] = __builtin_amdgcn_mfma_f32_16x16x32_bf16(pf[mt][ks2], vf, O[mt][nt2], 0, 0, 0);
      }
    }
    __syncthreads();  // done with Ks/Vt before next tile's staging
  }

  // ---- epilogue: O / l, write bf16 (feeds dense GEMM A-operand) ----
#pragma unroll
  for (int mt = 0; mt < 2; ++mt) {
    float inv[4];
#pragma unroll
    for (int i = 0; i < 4; ++i) inv[i] = 1.0f / l_i[mt][i];
#pragma unroll
    for (int nt2 = 0; nt2 < 8; ++nt2)
#pragma unroll
      for (int i = 0; i < 4; ++i) {
        size_t row = tok0 + q0 + mt * 64 + w * 16 + quad * 4 + i;
        out[row * H_ + h * HD_ + nt2 * 16 + l15] = f2bf(O[mt][nt2][i] * inv[i]);
      }
  }
}

// ---------------------------------------------------------------------------
// Workspace / buffer plan (ws need = 71.3 MB):
//   phase A (QKV GEMM):   ws[0,33.5M)   = hidden_bf16
//                         ws[33.5M,71.3M) = w_qkv^T bf16
//                         qkv bf16 (37.75 MB) -> lives in d_out (67 MB)
//   phase B (attn+dense): ws[0,2M)      = vt (V transposed bf16)
//                         ws[2M,35.7M)  = attn bf16
//                         ws[35.7M,69.2M) = w_dense^T bf16
//                         dense GEMM reads ws, writes d_out fp32 (no alias)
// ---------------------------------------------------------------------------
extern "C" void kernel_launch(void* const* d_in, const int* in_sizes, int n_in,
                              void* d_out, int out_size, void* d_ws, size_t ws_size,
                              hipStream_t stream)
{
  (void)in_sizes; (void)n_in; (void)out_size; (void)ws_size;
  const float* hidden    = (const float*)d_in[0];
  const float* w_qkv     = (const float*)d_in[1];
  const float* b_qkv     = (const float*)d_in[2];
  const float* w_dense   = (const float*)d_in[3];
  const int*   positions = (const int*)d_in[4];
  float* out = (float*)d_out;

  unsigned short* hbf   = (unsigned short*)d_ws;                      // 33.5 MB
  unsigned short* wqkvT = (unsigned short*)((char*)d_ws + 33554432);  // 37.75 MB
  unsigned short* vtb   = (unsigned short*)d_ws;                      // 2 MB (over dead hbf)
  unsigned short* abf   = (unsigned short*)((char*)d_ws + 2097152);   // 33.5 MB
  unsigned short* wdT   = (unsigned short*)((char*)d_ws + 35651584);  // 33.5 MB
  unsigned short* qkvb  = (unsigned short*)d_out;                     // 37.75 MB scratch in out

  // 1) convert hidden to bf16; transpose+convert w_qkv
  cvt_bf16_kernel<<<8192, 256, 0, stream>>>(hidden, hbf, (long)M_ * H_);
  wtrans_kernel<<<dim3(H_ / 64, NQKV_ / 64), 256, 0, stream>>>(w_qkv, wqkvT, H_, NQKV_);

  // 2) qkv = hidden @ w_qkv + b_qkv  (bf16 MFMA, bf16 out into d_out scratch)
  gemm_bf16_kernel<true><<<dim3(NQKV_ / 128, M_ / 128), 256, 0, stream>>>(
      hbf, wqkvT, b_qkv, qkvb, M_, NQKV_, H_);

  // 3) RoPE in-place (bf16 RMW)
  {
    int total = M_ * (NH_ + NKV_) * (ROT_ / 2);
    rope_kernel<<<(total + 255) / 256, 256, 0, stream>>>(qkvb, positions);
  }

  // 4) V transpose (bf16); transpose+convert w_dense (hbf/wqkvT now dead)
  vtrans_kernel<<<dim3(S_ / 64, HD_ / 64, B_ * NKV_), 256, 0, stream>>>(qkvb, vtb);
  wtrans_kernel<<<dim3(H_ / 64, H_ / 64), 256, 0, stream>>>(w_dense, wdT, H_, H_);

  // 5) causal GQA flash attention (bf16 MFMA, 128-row q-tiles), attn bf16
  flash_mfma_kernel<<<dim3(S_ / 128, B_ * NH_), 256, 0, stream>>>(qkvb, vtb, abf);

  // 6) out = attn @ w_dense (bf16 MFMA, fp32 out; overwrites qkv scratch)
  gemm_bf16_kernel<false><<<dim3(H_ / 128, M_ / 128), 256, 0, stream>>>(
      abf, wdT, nullptr, out, M_, H_, H_);
}

// Round 3
// 847.364 us; speedup vs baseline: 5.1017x; 1.0887x over previous
//
#include <hip/hip_runtime.h>
#include <math.h>

// Problem constants
#define B_    2
#define S_    2048
#define H_    4096
#define NH_   32
#define NKV_  2
#define HD_   128
#define ROT_  64
#define NQKV_ 4608          // (NH + 2*NKV) * HD
#define M_    4096          // B * S
#define SCALE_ 0.088388347648318447f  // 1/sqrt(128)

typedef __attribute__((ext_vector_type(8))) short s16x8;
typedef __attribute__((ext_vector_type(4))) float f32x4;

__device__ __forceinline__ unsigned short f2bf(float x) {
  union { float f; unsigned u; } v; v.f = x;
  unsigned r = (v.u + 0x7fffu + ((v.u >> 16) & 1u)) >> 16;
  return (unsigned short)r;
}
__device__ __forceinline__ float bf2f(unsigned short u) {
  union { unsigned u; float f; } v; v.u = ((unsigned)u) << 16;
  return v.f;
}
// async global->LDS, 16B per lane; LDS dest is wave-uniform base + lane*16
__device__ __forceinline__ void gl_lds16(const unsigned short* g, unsigned short* l) {
  __builtin_amdgcn_global_load_lds(
      (const __attribute__((address_space(1))) void*)g,
      (__attribute__((address_space(3))) void*)l, 16, 0, 0);
}

// ---------------------------------------------------------------------------
// fp32 -> bf16 elementwise convert (hidden_states). n must be multiple of 8.
// ---------------------------------------------------------------------------
__global__ __launch_bounds__(256) void cvt_bf16_kernel(
    const float* __restrict__ in, unsigned short* __restrict__ o, long n)
{
  long i = ((long)blockIdx.x * blockDim.x + threadIdx.x) * 8;
  if (i >= n) return;
  float4 a = *(const float4*)(in + i);
  float4 b = *(const float4*)(in + i + 4);
  s16x8 v;
  v[0] = f2bf(a.x); v[1] = f2bf(a.y); v[2] = f2bf(a.z); v[3] = f2bf(a.w);
  v[4] = f2bf(b.x); v[5] = f2bf(b.y); v[6] = f2bf(b.z); v[7] = f2bf(b.w);
  *(s16x8*)(o + i) = v;
}

// ---------------------------------------------------------------------------
// Weight transpose + convert: wt[n][k] (bf16, N x K row-major) <- w[k][n]
// (fp32, K x N row-major). 64x64 tiles through LDS. K,N multiples of 64.
// ---------------------------------------------------------------------------
__global__ __launch_bounds__(256) void wtrans_kernel(
    const float* __restrict__ w, unsigned short* __restrict__ wt, int K, int N)
{
  __shared__ __align__(16) unsigned short T[64][72];
  const int tid = threadIdx.x;
  const int k0 = blockIdx.x * 64;
  const int n0 = blockIdx.y * 64;

#pragma unroll
  for (int i = 0; i < 4; ++i) {
    int idx = tid + i * 256;
    int kr = idx >> 4;             // 0..63 (k within tile)
    int nc = (idx & 15) << 2;      // 0..60 step 4
    float4 v = *(const float4*)(w + (size_t)(k0 + kr) * N + n0 + nc);
    T[nc + 0][kr] = f2bf(v.x);
    T[nc + 1][kr] = f2bf(v.y);
    T[nc + 2][kr] = f2bf(v.z);
    T[nc + 3][kr] = f2bf(v.w);
  }
  __syncthreads();
#pragma unroll
  for (int i = 0; i < 2; ++i) {
    int idx = tid + i * 256;
    int nr = idx >> 3;             // 0..63
    int kc = (idx & 7) << 3;       // 0..56 step 8
    s16x8 v = *(const s16x8*)&T[nr][kc];
    *(s16x8*)&wt[(size_t)(n0 + nr) * K + k0 + kc] = v;
  }
}

// ---------------------------------------------------------------------------
// bf16 MFMA GEMM, 256x256 tile, 8 waves (2M x 4N), BK=32, counted-vmcnt
// phase pipeline (T3+T4+T5). C = A @ Bt^T (+bias).
// A: M x K bf16 row-major. Bt: N x K bf16 row-major.
// LDS 64KB: A-slots[2] @ 0/8192 shorts, B-slots[2] @ 16384/24576 shorts;
// slot = 256 rows x 32 k (k-slice layout -> conflict-free 1KB/wave ds_reads).
// Per tile: 2 phases {reads+1-half-stage | BAR | 16 MFMA | BAR}, one
// s_waitcnt vmcnt(2) per tile (never 0). Stagger: B(t+1)@ph0, A(t+2)@ph1.
// ---------------------------------------------------------------------------
template<bool BF16OUT>
__global__ __launch_bounds__(512, 1) void gemm256_kernel(
    const unsigned short* __restrict__ A, const unsigned short* __restrict__ Bt,
    const float* __restrict__ bias, void* __restrict__ Cv,
    int M, int N, int K)
{
  __shared__ __align__(16) unsigned short lds[32768];   // 64 KB
  const int tid  = threadIdx.x;
  const int lane = tid & 63;
  const int w    = tid >> 6;        // wave 0..7
  const int quad = lane >> 4;       // 0..3
  const int l15  = lane & 15;
  const int wm   = w >> 2;          // 0..1 (M half)
  const int wn   = w & 3;           // 0..3 (N quarter)
  const int bm = blockIdx.y * 256;
  const int bn = blockIdx.x * 256;
  const int NT = K >> 5;            // BK=32 tiles

  // stage source addressing: wave w covers rows w*32 + j*16 + (lane>>2)
  const unsigned short* Agl = A  + (size_t)(bm + w * 32 + (lane >> 2)) * K + ((lane & 3) << 3);
  const unsigned short* Bgl = Bt + (size_t)(bn + w * 32 + (lane >> 2)) * K + ((lane & 3) << 3);
  const size_t j1 = (size_t)16 * K;   // second 16-row group

  // fragment LDS offsets (shorts): contiguous 1KB per 16-row frag read
  const int afo = (wm * 128 + l15) * 32 + (quad << 3);  // + mi*512 + slot
  const int bfo = (wn * 64  + l15) * 32 + (quad << 3);  // + ni*512 + slot

  f32x4 acc[8][4];
#pragma unroll
  for (int i = 0; i < 8; ++i)
#pragma unroll
    for (int j = 0; j < 4; ++j)
#pragma unroll
      for (int e = 0; e < 4; ++e) acc[i][j][e] = 0.0f;

#define STAGE_A(T, BUF) do {                                            \
    const unsigned short* g_ = Agl + (size_t)(T) * 32;                  \
    gl_lds16(g_,      &lds[(BUF) * 8192 + w * 1024]);                   \
    gl_lds16(g_ + j1, &lds[(BUF) * 8192 + w * 1024 + 512]);             \
  } while (0)
#define STAGE_B(T, BUF) do {                                            \
    const unsigned short* g_ = Bgl + (size_t)(T) * 32;                  \
    gl_lds16(g_,      &lds[16384 + (BUF) * 8192 + w * 1024]);           \
    gl_lds16(g_ + j1, &lds[16384 + (BUF) * 8192 + w * 1024 + 512]);     \
  } while (0)

  // ---- prologue: A(0), B(0), A(1); wait A(0)+B(0) done, A(1) in flight ----
  STAGE_A(0, 0);
  STAGE_B(0, 0);
  STAGE_A(1, 1);
  asm volatile("s_waitcnt vmcnt(2)" ::: "memory");
  __builtin_amdgcn_s_barrier();
  __builtin_amdgcn_sched_barrier(0);

#define TILE_BODY(CUR, TT) do {                                              \
    const int nb_ = (CUR) ^ 1;                                               \
    /* ---- ph0: read af[8] + bf01; stage B(TT+1)->nb ---- */                \
    s16x8 af[8], b0, b1;                                                     \
    _Pragma("unroll")                                                        \
    for (int mi = 0; mi < 8; ++mi)                                           \
      af[mi] = *(const s16x8*)&lds[(CUR) * 8192 + afo + mi * 512];           \
    b0 = *(const s16x8*)&lds[16384 + (CUR) * 8192 + bfo];                    \
    b1 = *(const s16x8*)&lds[16384 + (CUR) * 8192 + bfo + 512];              \
    { int ts_ = (TT) + 1 < NT ? (TT) + 1 : NT - 1; STAGE_B(ts_, nb_); }      \
    __builtin_amdgcn_s_barrier();                                            \
    __builtin_amdgcn_sched_barrier(0);                                       \
    __builtin_amdgcn_s_setprio(1);                                           \
    _Pragma("unroll")                                                        \
    for (int mi = 0; mi < 8; ++mi) {                                         \
      acc[mi][0] = __builtin_amdgcn_mfma_f32_16x16x32_bf16(af[mi], b0, acc[mi][0], 0, 0, 0); \
      acc[mi][1] = __builtin_amdgcn_mfma_f32_16x16x32_bf16(af[mi], b1, acc[mi][1], 0, 0, 0); \
    }                                                                        \
    __builtin_amdgcn_s_setprio(0);                                           \
    __builtin_amdgcn_s_barrier();                                            \
    __builtin_amdgcn_sched_barrier(0);                                       \
    /* ---- ph1: read bf23; stage A(TT+2)->cur; wait vmcnt(2) ---- */        \
    s16x8 b2, b3;                                                            \
    b2 = *(const s16x8*)&lds[16384 + (CUR) * 8192 + bfo + 1024];             \
    b3 = *(const s16x8*)&lds[16384 + (CUR) * 8192 + bfo + 1536];             \
    { int ts_ = (TT) + 2 < NT ? (TT) + 2 : NT - 1; STAGE_A(ts_, (CUR)); }    \
    __builtin_amdgcn_s_barrier();                                            \
    __builtin_amdgcn_sched_barrier(0);                                       \
    __builtin_amdgcn_s_setprio(1);                                           \
    _Pragma("unroll")                                                        \
    for (int mi = 0; mi < 8; ++mi) {                                         \
      acc[mi][2] = __builtin_amdgcn_mfma_f32_16x16x32_bf16(af[mi], b2, acc[mi][2], 0, 0, 0); \
      acc[mi][3] = __builtin_amdgcn_mfma_f32_16x16x32_bf16(af[mi], b3, acc[mi][3], 0, 0, 0); \
    }                                                                        \
    __builtin_amdgcn_s_setprio(0);                                           \
    asm volatile("s_waitcnt vmcnt(2)" ::: "memory");                         \
    __builtin_amdgcn_s_barrier();                                            \
    __builtin_amdgcn_sched_barrier(0);                                       \
  } while (0)

#pragma unroll 1
  for (int t = 0; t < NT; t += 2) {
    TILE_BODY(0, t);
    TILE_BODY(1, t + 1);
  }
#undef TILE_BODY
#undef STAGE_A
#undef STAGE_B

  asm volatile("s_waitcnt vmcnt(0)" ::: "memory");  // drain clamped stages

  float bv[4];
#pragma unroll
  for (int ni = 0; ni < 4; ++ni)
    bv[ni] = bias ? bias[bn + wn * 64 + ni * 16 + l15] : 0.0f;

#pragma unroll
  for (int mi = 0; mi < 8; ++mi)
#pragma unroll
    for (int i = 0; i < 4; ++i) {
      size_t row = (size_t)(bm + wm * 128 + mi * 16 + (quad << 2) + i);
#pragma unroll
      for (int ni = 0; ni < 4; ++ni) {
        size_t idx = row * N + bn + wn * 64 + ni * 16 + l15;
        float val = acc[mi][ni][i] + bv[ni];
        if (BF16OUT) ((unsigned short*)Cv)[idx] = f2bf(val);
        else         ((float*)Cv)[idx] = val;
      }
    }
}

// ---------------------------------------------------------------------------
// RoPE (GLM interleaved, first ROT dims of q and k heads), in-place bf16.
// ---------------------------------------------------------------------------
__global__ __launch_bounds__(256) void rope_kernel(
    unsigned short* __restrict__ qkv, const int* __restrict__ positions)
{
  int t = blockIdx.x * blockDim.x + threadIdx.x;
  const int total = M_ * (NH_ + NKV_) * (ROT_ / 2);
  if (t >= total) return;
  int pair = t & 31;
  int hh   = (t >> 5) % (NH_ + NKV_);
  int tok  = t / (32 * (NH_ + NKV_));
  int col  = hh * HD_;
  float pos  = (float)positions[tok];
  float freq = powf(10000.0f, -(float)pair * (1.0f / 32.0f));
  float ang  = pos * freq;
  float s = sinf(ang), c = cosf(ang);
  size_t base = (size_t)tok * NQKV_ + col + 2 * pair;   // even -> 4B aligned
  unsigned v = *(const unsigned*)(qkv + base);
  float x1 = bf2f((unsigned short)(v & 0xffffu));
  float x2 = bf2f((unsigned short)(v >> 16));
  float o1 = x1 * c - x2 * s;
  float o2 = x1 * s + x2 * c;
  *(unsigned*)(qkv + base) = (unsigned)f2bf(o1) | ((unsigned)f2bf(o2) << 16);
}

// ---------------------------------------------------------------------------
// V transpose (bf16 -> bf16): vt[bg][c][s] <- qkv V part [b][s][g*128+c].
// 64x64 tiles through LDS; bg = b*NKV + g.
// ---------------------------------------------------------------------------
__global__ __launch_bounds__(256) void vtrans_kernel(
    const unsigned short* __restrict__ qkv, unsigned short* __restrict__ vt)
{
  __shared__ __align__(16) unsigned short T[64][72];
  const int tid = threadIdx.x;
  const int s0 = blockIdx.x * 64;
  const int c0 = blockIdx.y * 64;
  const int bg = blockIdx.z;
  const int b = bg >> 1, g = bg & 1;

#pragma unroll
  for (int i = 0; i < 2; ++i) {
    int idx = tid + i * 256;       // 0..511
    int sr = idx >> 3;             // 0..63 (token within tile)
    int cc = (idx & 7) << 3;       // 0..56 step 8
    const unsigned short* p = qkv + (size_t)(b * S_ + s0 + sr) * NQKV_
                     + (NH_ + NKV_) * HD_ + g * HD_ + c0 + cc;
    s16x8 v = *(const s16x8*)p;
#pragma unroll
    for (int j = 0; j < 8; ++j) T[cc + j][sr] = (unsigned short)v[j];
  }
  __syncthreads();
#pragma unroll
  for (int i = 0; i < 2; ++i) {
    int idx = tid + i * 256;
    int cr = idx >> 3;             // 0..63
    int kc = idx & 7;              // 16B chunk within 64 tokens
    s16x8 v = *(const s16x8*)&T[cr][kc << 3];
    *(s16x8*)&vt[(size_t)((bg << 7) + c0 + cr) * S_ + s0 + (kc << 3)] = v;
  }
}

// ---------------------------------------------------------------------------
// Flash attention, bf16 MFMA, causal, GQA. bf16 in (qkv), bf16 out (attn).
// Block: 128 q-rows of one (b,h), 4 waves; each wave owns two 16-row m-groups
// (rows mt*64 + w*16 .. +15). K-tiles of 64 keys.
// LDS (uint16 elements):
//   [0, 8704)        Ks[key][e], stride 136 (2-way conflicts only; also Q staging)
//   [8704, 16896)    Vt[col][key] 64 keys/row, XOR-chunk swizzle
//   [16896, 26112)   Ps[128 rows][stride 72]
// Shared kf/vf fragments feed both m-groups -> 2x MFMA per LDS read + per barrier.
// ---------------------------------------------------------------------------
#define VT_OFF 8704
#define PS_OFF 16896

__global__ __launch_bounds__(256, 2) void flash_mfma_kernel(
    const unsigned short* __restrict__ qkv, const unsigned short* __restrict__ vt,
    unsigned short* __restrict__ out)
{
  __shared__ __align__(16) unsigned short smem[26112];

  const int tid  = threadIdx.x;
  const int lane = tid & 63;
  const int w    = tid >> 6;        // wave 0..3
  const int quad = lane >> 4;       // 0..3
  const int l15  = lane & 15;
  const int q0 = blockIdx.x * 128;
  const int b  = blockIdx.y >> 5;
  const int h  = blockIdx.y & 31;
  const int g  = h >> 4;
  const int bg = b * NKV_ + g;
  const size_t tok0 = (size_t)b * S_;

  // ---- Stage Q (two 64-row halves through the Ks region), keep frags ----
  s16x8 qf[2][4];
#pragma unroll
  for (int mt = 0; mt < 2; ++mt) {
#pragma unroll
    for (int i = 0; i < 4; ++i) {
      int idx = tid + i * 256;                 // 0..1023
      int r = idx >> 4, c8 = (idx & 15) << 3;
      s16x8 v = *(const s16x8*)(qkv + (tok0 + q0 + mt * 64 + r) * NQKV_ + h * HD_ + c8);
      *(s16x8*)&smem[r * 136 + c8] = v;
    }
    __syncthreads();
#pragma unroll
    for (int ks = 0; ks < 4; ++ks)
      qf[mt][ks] = *(const s16x8*)&smem[(w * 16 + l15) * 136 + (quad << 3) + (ks << 5)];
    __syncthreads();  // all waves done reading before restage
  }

  f32x4 O[2][8];
#pragma unroll
  for (int mt = 0; mt < 2; ++mt)
#pragma unroll
    for (int n = 0; n < 8; ++n)
#pragma unroll
      for (int i = 0; i < 4; ++i) O[mt][n][i] = 0.0f;
  float m_i[2][4], l_i[2][4];
#pragma unroll
  for (int mt = 0; mt < 2; ++mt)
#pragma unroll
    for (int i = 0; i < 4; ++i) { m_i[mt][i] = -INFINITY; l_i[mt][i] = 0.f; }

  const int ktend = q0 + 64;   // rows reach q0+127 -> last k-tile starts at q0+64
  for (int kt = 0; kt <= ktend; kt += 64) {
    // ---- Stage K tile (64x128 bf16, pure copy) ----
#pragma unroll
    for (int i = 0; i < 4; ++i) {
      int idx = tid + i * 256;
      int key = idx >> 4, c8 = (idx & 15) << 3;
      s16x8 v = *(const s16x8*)(qkv + (tok0 + kt + key) * NQKV_ + NH_ * HD_ + g * HD_ + c8);
      *(s16x8*)&smem[key * 136 + c8] = v;
    }
    // ---- Stage V tile from pre-transposed bf16 (col-major, chunk swizzle) ----
#pragma unroll
    for (int i = 0; i < 4; ++i) {
      int idx = tid + i * 256;
      int c = idx >> 3, kc = idx & 7;
      s16x8 v = *(const s16x8*)&vt[(size_t)((bg << 7) + c) * S_ + kt + (kc << 3)];
      *(s16x8*)&smem[VT_OFF + (c << 6) + (((kc + c) & 7) << 3)] = v;
    }
    __syncthreads();

    // ---- S = Q K^T: kf shared by both m-groups ----
    f32x4 S[2][4];
#pragma unroll
    for (int mt = 0; mt < 2; ++mt)
#pragma unroll
      for (int nt = 0; nt < 4; ++nt)
#pragma unroll
        for (int i = 0; i < 4; ++i) S[mt][nt][i] = 0.0f;
#pragma unroll
    for (int nt = 0; nt < 4; ++nt) {
#pragma unroll
      for (int ks = 0; ks < 4; ++ks) {
        s16x8 kf = *(const s16x8*)&smem[(nt * 16 + l15) * 136 + (quad << 3) + (ks << 5)];
#pragma unroll
        for (int mt = 0; mt < 2; ++mt)
          S[mt][nt] = __builtin_amdgcn_mfma_f32_16x16x32_bf16(qf[mt][ks], kf, S[mt][nt], 0, 0, 0);
      }
#pragma unroll
      for (int mt = 0; mt < 2; ++mt)
#pragma unroll
        for (int i = 0; i < 4; ++i) S[mt][nt][i] *= SCALE_;
    }

    // ---- causal mask (only tiles at/past each m-group's diagonal) ----
#pragma unroll
    for (int mt = 0; mt < 2; ++mt) {
      if (kt >= q0 + mt * 64) {
#pragma unroll
        for (int nt = 0; nt < 4; ++nt) {
          int colG = kt + nt * 16 + l15;
#pragma unroll
          for (int i = 0; i < 4; ++i) {
            int rowG = q0 + mt * 64 + w * 16 + quad * 4 + i;
            if (colG > rowG) S[mt][nt][i] = -INFINITY;
          }
        }
      }
    }

    // ---- online softmax per m-group (rows = quad*4+i, reduce over l15 + nt) ----
    float alpha[2][4];
#pragma unroll
    for (int mt = 0; mt < 2; ++mt) {
      float mx[4], rs[4];
#pragma unroll
      for (int i = 0; i < 4; ++i) {
        mx[i] = fmaxf(fmaxf(S[mt][0][i], S[mt][1][i]), fmaxf(S[mt][2][i], S[mt][3][i]));
#pragma unroll
        for (int off = 1; off < 16; off <<= 1)
          mx[i] = fmaxf(mx[i], __shfl_xor(mx[i], off));
        float mn = fmaxf(m_i[mt][i], mx[i]);
        alpha[mt][i] = __expf(m_i[mt][i] - mn);   // exp(-inf)=0 on first tile
        m_i[mt][i] = mn;
        rs[i] = 0.0f;
      }
#pragma unroll
      for (int nt = 0; nt < 4; ++nt)
#pragma unroll
        for (int i = 0; i < 4; ++i) {
          float p = __expf(S[mt][nt][i] - m_i[mt][i]);
          S[mt][nt][i] = p;
          rs[i] += p;
        }
#pragma unroll
      for (int i = 0; i < 4; ++i) {
#pragma unroll
        for (int off = 1; off < 16; off <<= 1)
          rs[i] += __shfl_xor(rs[i], off);
        l_i[mt][i] = l_i[mt][i] * alpha[mt][i] + rs[i];
      }

      // ---- write P (bf16) to LDS, C-layout -> A-layout transform ----
#pragma unroll
      for (int nt = 0; nt < 4; ++nt)
#pragma unroll
        for (int i = 0; i < 4; ++i)
          smem[PS_OFF + (mt * 64 + w * 16 + quad * 4 + i) * 72 + nt * 16 + l15]
              = f2bf(S[mt][nt][i]);

      // ---- rescale O ----
#pragma unroll
      for (int n = 0; n < 8; ++n)
#pragma unroll
        for (int i = 0; i < 4; ++i) O[mt][n][i] *= alpha[mt][i];
    }

    __syncthreads();  // Ps visible (and keeps waves off next staging)

    // ---- O += P V : vf shared by both m-groups ----
    s16x8 pf[2][2];
#pragma unroll
    for (int mt = 0; mt < 2; ++mt)
#pragma unroll
      for (int ks2 = 0; ks2 < 2; ++ks2)
        pf[mt][ks2] = *(const s16x8*)&smem[PS_OFF + (mt * 64 + w * 16 + l15) * 72
                                           + (quad << 3) + (ks2 << 5)];
#pragma unroll
    for (int nt2 = 0; nt2 < 8; ++nt2) {
      int col = nt2 * 16 + l15;
#pragma unroll
      for (int ks2 = 0; ks2 < 2; ++ks2) {
        int kc = ks2 * 4 + quad;
        s16x8 vf = *(const s16x8*)&smem[VT_OFF + (col << 6) + (((kc + col) & 7) << 3)];
#pragma unroll
        for (int mt = 0; mt < 2; ++mt)
          O[mt][nt2] = __builtin_amdgcn_mfma_f32_16x16x32_bf16(pf[mt][ks2], vf, O[mt][nt2], 0, 0, 0);
      }
    }
    __syncthreads();  // done with Ks/Vt before next tile's staging
  }

  // ---- epilogue: O / l, write bf16 (feeds dense GEMM A-operand) ----
#pragma unroll
  for (int mt = 0; mt < 2; ++mt) {
    float inv[4];
#pragma unroll
    for (int i = 0; i < 4; ++i) inv[i] = 1.0f / l_i[mt][i];
#pragma unroll
    for (int nt2 = 0; nt2 < 8; ++nt2)
#pragma unroll
      for (int i = 0; i < 4; ++i) {
        size_t row = tok0 + q0 + mt * 64 + w * 16 + quad * 4 + i;
        out[row * H_ + h * HD_ + nt2 * 16 + l15] = f2bf(O[mt][nt2][i] * inv[i]);
      }
  }
}

// ---------------------------------------------------------------------------
// Workspace / buffer plan (ws need = 71.3 MB):
//   phase A (QKV GEMM):   ws[0,33.5M)   = hidden_bf16
//                         ws[33.5M,71.3M) = w_qkv^T bf16
//                         qkv bf16 (37.75 MB) -> lives in d_out (67 MB)
//   phase B (attn+dense): ws[0,2M)      = vt (V transposed bf16)
//                         ws[2M,35.7M)  = attn bf16
//                         ws[35.7M,69.2M) = w_dense^T bf16
//                         dense GEMM reads ws, writes d_out fp32 (no alias)
// ---------------------------------------------------------------------------
extern "C" void kernel_launch(void* const* d_in, const int* in_sizes, int n_in,
                              void* d_out, int out_size, void* d_ws, size_t ws_size,
                              hipStream_t stream)
{
  (void)in_sizes; (void)n_in; (void)out_size; (void)ws_size;
  const float* hidden    = (const float*)d_in[0];
  const float* w_qkv     = (const float*)d_in[1];
  const float* b_qkv     = (const float*)d_in[2];
  const float* w_dense   = (const float*)d_in[3];
  const int*   positions = (const int*)d_in[4];
  float* out = (float*)d_out;

  unsigned short* hbf   = (unsigned short*)d_ws;                      // 33.5 MB
  unsigned short* wqkvT = (unsigned short*)((char*)d_ws + 33554432);  // 37.75 MB
  unsigned short* vtb   = (unsigned short*)d_ws;                      // 2 MB (over dead hbf)
  unsigned short* abf   = (unsigned short*)((char*)d_ws + 2097152);   // 33.5 MB
  unsigned short* wdT   = (unsigned short*)((char*)d_ws + 35651584);  // 33.5 MB
  unsigned short* qkvb  = (unsigned short*)d_out;                     // 37.75 MB scratch in out

  // 1) convert hidden to bf16; transpose+convert w_qkv
  cvt_bf16_kernel<<<8192, 256, 0, stream>>>(hidden, hbf, (long)M_ * H_);
  wtrans_kernel<<<dim3(H_ / 64, NQKV_ / 64), 256, 0, stream>>>(w_qkv, wqkvT, H_, NQKV_);

  // 2) qkv = hidden @ w_qkv + b_qkv  (bf16 MFMA, bf16 out into d_out scratch)
  gemm256_kernel<true><<<dim3(NQKV_ / 256, M_ / 256), 512, 0, stream>>>(
      hbf, wqkvT, b_qkv, qkvb, M_, NQKV_, H_);

  // 3) RoPE in-place (bf16 RMW)
  {
    int total = M_ * (NH_ + NKV_) * (ROT_ / 2);
    rope_kernel<<<(total + 255) / 256, 256, 0, stream>>>(qkvb, positions);
  }

  // 4) V transpose (bf16); transpose+convert w_dense (hbf/wqkvT now dead)
  vtrans_kernel<<<dim3(S_ / 64, HD_ / 64, B_ * NKV_), 256, 0, stream>>>(qkvb, vtb);
  wtrans_kernel<<<dim3(H_ / 64, H_ / 64), 256, 0, stream>>>(w_dense, wdT, H_, H_);

  // 5) causal GQA flash attention (bf16 MFMA, 128-row q-tiles), attn bf16
  flash_mfma_kernel<<<dim3(S_ / 128, B_ * NH_), 256, 0, stream>>>(qkvb, vtb, abf);

  // 6) out = attn @ w_dense (bf16 MFMA, fp32 out; overwrites qkv scratch)
  gemm256_kernel<false><<<dim3(H_ / 256, M_ / 256), 512, 0, stream>>>(
      abf, wdT, nullptr, out, M_, H_, H_);
}